// Round 19
// baseline (36.046 us; speedup 1.0000x reference)
//
#include <hip/hip_runtime.h>

// Denoiser MLP (2->16, 5x 16->16, 16->2), fp32 in/out.
// R19: swap legacy v_mfma_f32_16x16x16_f16 (~13.5 cyc/instr measured via
// MfmaUtil R3/R5) for gfx950-native v_mfma_f32_16x16x32_f16 (~5 cyc, m64)
// with ZERO-PADDED k-space: per lane A=[W_row cols 4g..4g+3 | 0,0,0,0],
// B=[feats 4g..4g+3 | 0,0,0,0]. A,B share the k<->(g,j) mapping, so j0-3
// columns are distinct per group and the zero half annihilates exactly
// (both sides zeroed -> no NaN). Computes the identical 16x16 product;
// D layout identical (m89: row=4*(lane>>4)+reg, col=lane&15) -> same
// in-register chaining. Matrix-pipe demand 10.8us -> ~4us; sum-model
// (dur ~= MFMA + VALU + mem = 27.3 ~= measured 27.7) predicts ~20us.
//
// Structure: R17's 4 chains/wave (reg audit ~100 -> lb(256,4)) + R18's
// wo_t coalesced store + persistent grid + depth-1 prefetch.
//   A frag (16x16x32): lane l slots j0-3 = own quad, j4-7 = 0
//   B frag: same k mapping; j0-3 real, j4-7 = 0
//   D frag: lane l holds D[i=4*(l>>4)+r][n=l&15], r=0..3
// Input trick: bin=[cvtpk(x,y),0,0,0]; wi_t = W_in at group-t's j0,j1
// columns (held by g==t lanes) -> selects group-t lanes' points.
// Output trick: wo_t = W_out rows at A-rows {4t,4t+1} -> tile t's result
// lands at lane-group t regs 0,1 -> cndmask select -> coalesced 512B store.

typedef _Float16 h8 __attribute__((ext_vector_type(8)));
typedef _Float16 h4v __attribute__((ext_vector_type(4)));
typedef float f4 __attribute__((ext_vector_type(4)));
typedef float f2 __attribute__((ext_vector_type(2)));
typedef unsigned int u32;
typedef u32 u2v __attribute__((ext_vector_type(2)));
typedef u32 u4v __attribute__((ext_vector_type(4)));

static __device__ __forceinline__ f4 mfma32k(h8 a, h8 b, f4 c) {
    return __builtin_amdgcn_mfma_f32_16x16x32_f16(a, b, c, 0, 0, 0);
}

static __device__ __forceinline__ u32 cvtpk(float a, float b) {
    return __builtin_bit_cast(u32, __builtin_amdgcn_cvt_pkrtz(a, b));
}

static __device__ __forceinline__ h8 pack4(u32 a, u32 b, u32 c, u32 d) {
    u4v p = {a, b, c, d};
    return __builtin_bit_cast(h8, p);
}

// weight A-fragment: row's cols 4g..4g+3 in j0-3, zeros in j4-7
static __device__ __forceinline__ h8 wfrag(const float* row, int g) {
    const f4* r4 = (const f4*)row;
    f4 q = r4[g];
    return pack4(cvtpk(q.x, q.y), cvtpk(q.z, q.w), 0u, 0u);
}

// relu + cvt of D regs 0-3 -> next layer's B fragment (j0-3 real, j4-7 = 0)
static __device__ __forceinline__ h8 cvt_relu4(f4 a) {
    u2v c = { cvtpk(a[0], a[1]), cvtpk(a[2], a[3]) };
    h4v hb = __builtin_bit_cast(h4v, c);
    const h4v z = {};
    hb = __builtin_elementwise_max(hb, z);   // 2x v_pk_max_f16
    u2v r = __builtin_bit_cast(u2v, hb);
    return pack4(r.x, r.y, 0u, 0u);
}

__global__ __launch_bounds__(256, 4) void denoiser_mfma16k32(
    const f2* __restrict__ x,        // [N] points (x0,x1)
    const float* __restrict__ w_in,  // [16][2]
    const float* __restrict__ w_mid, // [5][16][16]
    const float* __restrict__ w_out, // [2][16]
    f2* __restrict__ out,            // [N] (o0,o1)
    int n)
{
    const int lane = threadIdx.x & 63;
    const int nn   = lane & 15;   // A-row / point-in-tile
    const int g    = lane >> 4;   // k-group
    const int wave = threadIdx.x >> 6;

    const h8 hz = {};

    // ---- one-time weight fragments ----
    // input variants: wi_t nonzero only for g==t lanes (its j0,j1 columns)
    u32 wxy = cvtpk(w_in[2 * nn], w_in[2 * nn + 1]);
    h8 wiv = pack4(wxy, 0u, 0u, 0u);
    h8 wi0 = g == 0 ? wiv : hz;
    h8 wi1 = g == 1 ? wiv : hz;
    h8 wi2 = g == 2 ? wiv : hz;
    h8 wi3 = g == 3 ? wiv : hz;

    h8 wm0 = wfrag(w_mid + 0 * 256 + nn * 16, g);
    h8 wm1 = wfrag(w_mid + 1 * 256 + nn * 16, g);
    h8 wm2 = wfrag(w_mid + 2 * 256 + nn * 16, g);
    h8 wm3 = wfrag(w_mid + 3 * 256 + nn * 16, g);
    h8 wm4 = wfrag(w_mid + 4 * 256 + nn * 16, g);

    // output variants: W_out row (nn&3) at A-rows {4t,4t+1}, t = nn>>2
    h8 wofull = (nn & 3) < 2 ? wfrag(w_out + (nn & 3) * 16, g) : hz;
    int tsel = nn >> 2;
    h8 wo0 = tsel == 0 ? wofull : hz;
    h8 wo1 = tsel == 1 ? wofull : hz;
    h8 wo2 = tsel == 2 ? wofull : hz;
    h8 wo3 = tsel == 3 ? wofull : hz;

    // one-time pin: zero C-operand resident, un-rematerializable
    f4 z4 = {};
    asm("" : "+v"(z4));

    const int nchunks = (n + 255) >> 8;     // 256 pts per block-iteration
    const int stride  = gridDim.x;
    const int nm1     = n - 1;

    auto loadx = [&](int c) -> f2 {
        int pi = c * 256 + wave * 64 + lane;
        return x[pi < n ? pi : nm1];
    };

    // select a_g's regs 0,1 by lane group (cndmask chain)
    auto selstore = [&](f4 a0, f4 a1, f4 a2, f4 a3) -> f2 {
        float s0 = g < 2 ? (g == 1 ? a1[0] : a0[0]) : (g == 3 ? a3[0] : a2[0]);
        float s1 = g < 2 ? (g == 1 ? a1[1] : a0[1]) : (g == 3 ? a3[1] : a2[1]);
        return (f2){s0, s1};
    };

    int c = blockIdx.x;
    f2 xy = loadx(c);

    for (; c < nchunks; c += stride) {
        const int cn = c + stride;
        f2 xyn = loadx(cn < nchunks ? cn : c);

        const int base = c * 256 + wave * 64;

        // ---- input layer: one bin, 4 group-selecting A variants ----
        h8 bin = pack4(cvtpk(xy.x, xy.y), 0u, 0u, 0u);
        f4 a0 = mfma32k(wi0, bin, z4);   // pts base+ 0..15
        f4 a1 = mfma32k(wi1, bin, z4);   // pts base+16..31
        f4 a2 = mfma32k(wi2, bin, z4);   // pts base+32..47
        f4 a3 = mfma32k(wi3, bin, z4);   // pts base+48..63
        h8 b0 = cvt_relu4(a0);
        h8 b1 = cvt_relu4(a1);
        h8 b2 = cvt_relu4(a2);
        h8 b3 = cvt_relu4(a3);

        // ---- 5 mid layers: 4 independent chains ----
        #define MIDLAYER(W)                                      \
            a0 = mfma32k(W, b0, z4);  a1 = mfma32k(W, b1, z4);   \
            a2 = mfma32k(W, b2, z4);  a3 = mfma32k(W, b3, z4);   \
            b0 = cvt_relu4(a0);  b1 = cvt_relu4(a1);             \
            b2 = cvt_relu4(a2);  b3 = cvt_relu4(a3);
        MIDLAYER(wm0)
        MIDLAYER(wm1)
        MIDLAYER(wm2)
        MIDLAYER(wm3)
        MIDLAYER(wm4)
        #undef MIDLAYER

        // ---- output layer: wo_t routes tile t's rows to lane-group t ----
        a0 = mfma32k(wo0, b0, z4);
        a1 = mfma32k(wo1, b1, z4);
        a2 = mfma32k(wo2, b2, z4);
        a3 = mfma32k(wo3, b3, z4);

        f2 o = selstore(a0, a1, a2, a3);   // point base + lane

        if (base + 64 <= n) {
            out[base + lane] = o;          // one 512B contiguous line/wave
        } else if (base + lane < n) {
            out[base + lane] = o;
        }

        xy = xyn;
    }
}

extern "C" void kernel_launch(void* const* d_in, const int* in_sizes, int n_in,
                              void* d_out, int out_size, void* d_ws, size_t ws_size,
                              hipStream_t stream) {
    const float* x     = (const float*)d_in[0];
    const float* w_in  = (const float*)d_in[1];
    const float* w_mid = (const float*)d_in[2];
    const float* w_out = (const float*)d_in[3];

    int n = in_sizes[0] / 2;          // number of points
    int nchunks = (n + 255) / 256;
    int blocks = nchunks < 2048 ? nchunks : 2048;  // persistent

    denoiser_mfma16k32<<<blocks, 256, 0, stream>>>(
        (const f2*)x, w_in, w_mid, w_out, (f2*)d_out, n);
}

// Round 20
// 28.507 us; speedup vs baseline: 1.2645x; 1.2645x over previous
//
#include <hip/hip_runtime.h>

// Denoiser MLP (2->16, 5x 16->16, 16->2), fp32 in/out, via v_mfma_f32_16x16x16_f16.
// R20: overlap attack. R19 taught: legacy 16x16x16 is the FASTEST shape per
// useful FLOP for a 16x16 matrix (13.45 cyc/SIMD vs K=32-padded 20.6,
// 32x32-dup 32.3) -> matrix term ~10us irreducible. Measured 27.7 fits the
// ADDITIVE model (matrix 10 + VALU 6 + mem 8): pipes alternate, don't
// overlap -- homogeneous waves, no barriers, oldest-first arbitration keeps
// them in phase. Fixes:
//  - T5 s_setprio(1) around each MFMA cluster (m191: helps independent-wave
//    kernels; m190's null was barrier-locked GEMM -- we have no barriers):
//    MFMA-phase waves win issue arbitration -> phases decorrelate.
//  - depth-2 x prefetch (~1300 cyc ahead, covers cold-HBM ~900 cyc).
// Base = R18 (8 chains, lb(256,4), coalesced wo_t stores; == R17 perf).
//
// Mapping (verified R3/R17/R18, absmax 7.8e-3):
//   A frag: lane l holds A[i=l&15][k=4*(l>>4)+j]; B: B[k=4g+j][n=l&15]
//   D frag: lane l holds D[i=4*(l>>4)+r][n=l&15] == B layout -> in-register
//   layer chaining, zero cross-lane.
// Input trick: bin = pack2(cvtpk(x,y),0) puts lane's point at k=4g+{0,1};
// wi_t (W_in at k-slots {4t,4t+1}, g==t lanes) selects group-t points.
// Output trick: wo_t (W_out rows at A-rows {4t,4t+1}) -> tile t's rows 0,1
// land at lane-group t -> cndmask select -> coalesced 512B line store.

typedef _Float16 h4v __attribute__((ext_vector_type(4)));
typedef float f4 __attribute__((ext_vector_type(4)));
typedef float f2 __attribute__((ext_vector_type(2)));
typedef unsigned int u32;
typedef u32 u2v __attribute__((ext_vector_type(2)));

static __device__ __forceinline__ f4 mfma16(h4v a, h4v b, f4 c) {
    return __builtin_amdgcn_mfma_f32_16x16x16f16(a, b, c, 0, 0, 0);
}

static __device__ __forceinline__ u32 cvtpk(float a, float b) {
    return __builtin_bit_cast(u32, __builtin_amdgcn_cvt_pkrtz(a, b));
}

static __device__ __forceinline__ h4v pack2(u32 lo, u32 hi) {
    u2v p = {lo, hi};
    return __builtin_bit_cast(h4v, p);
}

static __device__ __forceinline__ h4v wfrag(const float* row, int g) {
    const f4* r4 = (const f4*)row;
    f4 q = r4[g];
    return pack2(cvtpk(q.x, q.y), cvtpk(q.z, q.w));
}

static __device__ __forceinline__ h4v cvt_relu4(f4 a) {
    h4v hb = pack2(cvtpk(a[0], a[1]), cvtpk(a[2], a[3]));
    const h4v z = {};
    return __builtin_elementwise_max(hb, z);   // 2x v_pk_max_f16
}

__global__ __launch_bounds__(256, 4) void denoiser_mfma16(
    const f2* __restrict__ x,        // [N] points (x0,x1)
    const float* __restrict__ w_in,  // [16][2]
    const float* __restrict__ w_mid, // [5][16][16]
    const float* __restrict__ w_out, // [2][16]
    f2* __restrict__ out,            // [N] (o0,o1)
    int n)
{
    const int lane = threadIdx.x & 63;
    const int nn   = lane & 15;
    const int g    = lane >> 4;
    const int wave = threadIdx.x >> 6;

    const h4v hz = {};

    // ---- one-time weight fragments ----
    u32 wxy = cvtpk(w_in[2 * nn], w_in[2 * nn + 1]);
    h4v wiv = pack2(wxy, 0u);
    h4v wi0 = g == 0 ? wiv : hz;
    h4v wi1 = g == 1 ? wiv : hz;
    h4v wi2 = g == 2 ? wiv : hz;
    h4v wi3 = g == 3 ? wiv : hz;

    h4v wm0 = wfrag(w_mid + 0 * 256 + nn * 16, g);
    h4v wm1 = wfrag(w_mid + 1 * 256 + nn * 16, g);
    h4v wm2 = wfrag(w_mid + 2 * 256 + nn * 16, g);
    h4v wm3 = wfrag(w_mid + 3 * 256 + nn * 16, g);
    h4v wm4 = wfrag(w_mid + 4 * 256 + nn * 16, g);

    h4v wofull = (nn & 3) < 2 ? wfrag(w_out + (nn & 3) * 16, g) : hz;
    int tsel = nn >> 2;
    h4v wo0 = tsel == 0 ? wofull : hz;
    h4v wo1 = tsel == 1 ? wofull : hz;
    h4v wo2 = tsel == 2 ? wofull : hz;
    h4v wo3 = tsel == 3 ? wofull : hz;

    f4 z4 = {};
    asm("" : "+v"(z4));

    const int nchunks = (n + 511) >> 9;     // 512 pts per block-iteration
    const int stride  = gridDim.x;
    const int nm1     = n - 1;

    auto loadx = [&](int c, int half) -> f2 {
        int pi = c * 512 + wave * 128 + half * 64 + lane;
        return x[pi < n ? pi : nm1];
    };

    auto selstore = [&](f4 a0, f4 a1, f4 a2, f4 a3) -> f2 {
        float s0 = g < 2 ? (g == 1 ? a1[0] : a0[0]) : (g == 3 ? a3[0] : a2[0]);
        float s1 = g < 2 ? (g == 1 ? a1[1] : a0[1]) : (g == 3 ? a3[1] : a2[1]);
        return (f2){s0, s1};
    };

    // ---- depth-2 prefetch pipeline ----
    int c = blockIdx.x;
    const int c1 = c + stride < nchunks ? c + stride : c;
    f2 xyA0 = loadx(c, 0),  xyB0 = loadx(c, 1);
    f2 xyA1 = loadx(c1, 0), xyB1 = loadx(c1, 1);

    for (; c < nchunks; c += stride) {
        const int cpp = c + 2 * stride < nchunks ? c + 2 * stride : c;
        f2 xyA2 = loadx(cpp, 0);
        f2 xyB2 = loadx(cpp, 1);

        const int base = c * 512 + wave * 128;
        const bool full = (base + 128 <= n);

        // ---- input layer ----
        h4v binA = pack2(cvtpk(xyA0.x, xyA0.y), 0u);
        h4v binB = pack2(cvtpk(xyB0.x, xyB0.y), 0u);
        __builtin_amdgcn_s_setprio(1);
        f4 a0 = mfma16(wi0, binA, z4);
        f4 a1 = mfma16(wi1, binA, z4);
        f4 a2 = mfma16(wi2, binA, z4);
        f4 a3 = mfma16(wi3, binA, z4);
        f4 a4 = mfma16(wi0, binB, z4);
        f4 a5 = mfma16(wi1, binB, z4);
        f4 a6 = mfma16(wi2, binB, z4);
        f4 a7 = mfma16(wi3, binB, z4);
        __builtin_amdgcn_s_setprio(0);
        h4v b0 = cvt_relu4(a0), b1 = cvt_relu4(a1);
        h4v b2 = cvt_relu4(a2), b3 = cvt_relu4(a3);
        h4v b4 = cvt_relu4(a4), b5 = cvt_relu4(a5);
        h4v b6 = cvt_relu4(a6), b7 = cvt_relu4(a7);

        // ---- 5 mid layers: 8 independent chains ----
        #define MIDLAYER(W)                                        \
            __builtin_amdgcn_s_setprio(1);                         \
            a0 = mfma16(W, b0, z4);  a1 = mfma16(W, b1, z4);       \
            a2 = mfma16(W, b2, z4);  a3 = mfma16(W, b3, z4);       \
            a4 = mfma16(W, b4, z4);  a5 = mfma16(W, b5, z4);       \
            a6 = mfma16(W, b6, z4);  a7 = mfma16(W, b7, z4);       \
            __builtin_amdgcn_s_setprio(0);                         \
            b0 = cvt_relu4(a0);  b1 = cvt_relu4(a1);               \
            b2 = cvt_relu4(a2);  b3 = cvt_relu4(a3);               \
            b4 = cvt_relu4(a4);  b5 = cvt_relu4(a5);               \
            b6 = cvt_relu4(a6);  b7 = cvt_relu4(a7);
        MIDLAYER(wm0)
        MIDLAYER(wm1)
        MIDLAYER(wm2)
        MIDLAYER(wm3)
        MIDLAYER(wm4)
        #undef MIDLAYER

        // ---- output layer ----
        __builtin_amdgcn_s_setprio(1);
        a0 = mfma16(wo0, b0, z4);
        a1 = mfma16(wo1, b1, z4);
        a2 = mfma16(wo2, b2, z4);
        a3 = mfma16(wo3, b3, z4);
        a4 = mfma16(wo0, b4, z4);
        a5 = mfma16(wo1, b5, z4);
        a6 = mfma16(wo2, b6, z4);
        a7 = mfma16(wo3, b7, z4);
        __builtin_amdgcn_s_setprio(0);

        f2 oA = selstore(a0, a1, a2, a3);
        f2 oB = selstore(a4, a5, a6, a7);

        if (full) {
            out[base + lane]      = oA;
            out[base + 64 + lane] = oB;
        } else {
            if (base + lane < n)      out[base + lane]      = oA;
            if (base + 64 + lane < n) out[base + 64 + lane] = oB;
        }

        xyA0 = xyA1; xyB0 = xyB1;
        xyA1 = xyA2; xyB1 = xyB2;
    }
}

extern "C" void kernel_launch(void* const* d_in, const int* in_sizes, int n_in,
                              void* d_out, int out_size, void* d_ws, size_t ws_size,
                              hipStream_t stream) {
    const float* x     = (const float*)d_in[0];
    const float* w_in  = (const float*)d_in[1];
    const float* w_mid = (const float*)d_in[2];
    const float* w_out = (const float*)d_in[3];

    int n = in_sizes[0] / 2;          // number of points
    int nchunks = (n + 511) / 512;
    int blocks = nchunks < 2048 ? nchunks : 2048;  // persistent

    denoiser_mfma16<<<blocks, 256, 0, stream>>>(
        (const f2*)x, w_in, w_mid, w_out, (f2*)d_out, n);
}

// Round 21
// 28.242 us; speedup vs baseline: 1.2763x; 1.0094x over previous
//
#include <hip/hip_runtime.h>

// Denoiser MLP (2->16, 5x 16->16, 16->2), fp32 in/out, via v_mfma_f32_16x16x16_f16.
// R21: last three independent levers on the R17 base (27.66us best):
//  1. lb(256,6): R17's ~70-reg audit fits 85-reg budget -> 6 waves/SIMD.
//  2. s_sleep(wave) entry stagger (0/64/128/192 cyc): same-SIMD waves run an
//     identical ~700-cyc body under fair round-robin -> relative phase is
//     constant forever; if starts cluster, MFMA bursts collide every body.
//     Quarter-body offsets by construction; 1 scalar instr, 0 registers.
//  3. R18's wo_t output variants -> coalesced 512B line store (2 stores vs
//     8 masked); neutral at 8-chain pressure, retry at 4-chain pressure.
// Additive model (fits R17-R20): dur ~= matrix 10 + VALU 6.5 + mem 8-10.
//
// Mapping (verified R3/R17/R18, absmax 7.8e-3):
//   A frag: lane l holds A[i=l&15][k=4*(l>>4)+j]; B: B[k=4g+j][n=l&15]
//   D frag: lane l holds D[i=4*(l>>4)+r][n=l&15] == B layout -> in-register
//   layer chaining, zero cross-lane.
// Input trick: bin = pack2(cvtpk(x,y),0) puts lane's point at k=4g+{0,1};
// wi_t (W_in at k-slots {4t,4t+1}, g==t lanes) selects group-t points.
// Output trick: wo_t (W_out rows at A-rows {4t,4t+1}) -> tile t's rows 0,1
// land at lane-group t -> cndmask select -> one contiguous 512B store/wave.

typedef _Float16 h4v __attribute__((ext_vector_type(4)));
typedef float f4 __attribute__((ext_vector_type(4)));
typedef float f2 __attribute__((ext_vector_type(2)));
typedef unsigned int u32;
typedef u32 u2v __attribute__((ext_vector_type(2)));

static __device__ __forceinline__ f4 mfma16(h4v a, h4v b, f4 c) {
    return __builtin_amdgcn_mfma_f32_16x16x16f16(a, b, c, 0, 0, 0);
}

static __device__ __forceinline__ u32 cvtpk(float a, float b) {
    return __builtin_bit_cast(u32, __builtin_amdgcn_cvt_pkrtz(a, b));
}

static __device__ __forceinline__ h4v pack2(u32 lo, u32 hi) {
    u2v p = {lo, hi};
    return __builtin_bit_cast(h4v, p);
}

static __device__ __forceinline__ h4v wfrag(const float* row, int g) {
    const f4* r4 = (const f4*)row;
    f4 q = r4[g];
    return pack2(cvtpk(q.x, q.y), cvtpk(q.z, q.w));
}

static __device__ __forceinline__ h4v cvt_relu4(f4 a) {
    h4v hb = pack2(cvtpk(a[0], a[1]), cvtpk(a[2], a[3]));
    const h4v z = {};
    return __builtin_elementwise_max(hb, z);   // 2x v_pk_max_f16
}

__global__ __launch_bounds__(256, 6) void denoiser_mfma16(
    const f2* __restrict__ x,        // [N] points (x0,x1)
    const float* __restrict__ w_in,  // [16][2]
    const float* __restrict__ w_mid, // [5][16][16]
    const float* __restrict__ w_out, // [2][16]
    f2* __restrict__ out,            // [N] (o0,o1)
    int n)
{
    const int lane = threadIdx.x & 63;
    const int nn   = lane & 15;   // A-row / point-in-tile
    const int g    = lane >> 4;   // k-group / output-row group
    const int wave = threadIdx.x >> 6;

    // ---- phase stagger: quarter-body offsets between co-resident waves ----
    if (wave == 1) __builtin_amdgcn_s_sleep(1);        // ~64 cyc
    else if (wave == 2) __builtin_amdgcn_s_sleep(2);   // ~128 cyc
    else if (wave == 3) __builtin_amdgcn_s_sleep(3);   // ~192 cyc

    const h4v hz = {};

    // ---- one-time weight fragments ----
    u32 wxy = cvtpk(w_in[2 * nn], w_in[2 * nn + 1]);
    h4v wiv = pack2(wxy, 0u);
    h4v wi0 = g == 0 ? wiv : hz;
    h4v wi1 = g == 1 ? wiv : hz;
    h4v wi2 = g == 2 ? wiv : hz;
    h4v wi3 = g == 3 ? wiv : hz;

    h4v wm0 = wfrag(w_mid + 0 * 256 + nn * 16, g);
    h4v wm1 = wfrag(w_mid + 1 * 256 + nn * 16, g);
    h4v wm2 = wfrag(w_mid + 2 * 256 + nn * 16, g);
    h4v wm3 = wfrag(w_mid + 3 * 256 + nn * 16, g);
    h4v wm4 = wfrag(w_mid + 4 * 256 + nn * 16, g);

    // output variants: W_out row (nn&3) at A-rows {4t,4t+1}, t = nn>>2
    h4v wofull = (nn & 3) < 2 ? wfrag(w_out + (nn & 3) * 16, g) : hz;
    int tsel = nn >> 2;
    h4v wo0 = tsel == 0 ? wofull : hz;
    h4v wo1 = tsel == 1 ? wofull : hz;
    h4v wo2 = tsel == 2 ? wofull : hz;
    h4v wo3 = tsel == 3 ? wofull : hz;

    // one-time pin: zero C-operand resident, un-rematerializable
    f4 z4 = {};
    asm("" : "+v"(z4));

    const int nchunks = (n + 255) >> 8;     // 256-pt block chunks
    const int stride  = gridDim.x;
    const int nm1     = n - 1;

    auto loadx = [&](int c) -> f2 {
        int pi = c * 256 + wave * 64 + lane;
        return x[pi < n ? pi : nm1];
    };

    // select a_g's regs 0,1 by lane group (cndmask chain)
    auto selstore = [&](f4 a0, f4 a1, f4 a2, f4 a3) -> f2 {
        float s0 = g < 2 ? (g == 1 ? a1[0] : a0[0]) : (g == 3 ? a3[0] : a2[0]);
        float s1 = g < 2 ? (g == 1 ? a1[1] : a0[1]) : (g == 3 ? a3[1] : a2[1]);
        return (f2){s0, s1};
    };

    int c = blockIdx.x;
    f2 xy = loadx(c);

    for (; c < nchunks; c += stride) {
        const int cn = c + stride;
        f2 xyn = loadx(cn < nchunks ? cn : c);

        const int base = c * 256 + wave * 64;

        // ---- input layer: one bin, 4 group-selecting A variants ----
        h4v bin = pack2(cvtpk(xy.x, xy.y), 0u);
        f4 a0 = mfma16(wi0, bin, z4);   // pts base+ 0..15
        f4 a1 = mfma16(wi1, bin, z4);   // pts base+16..31
        f4 a2 = mfma16(wi2, bin, z4);   // pts base+32..47
        f4 a3 = mfma16(wi3, bin, z4);   // pts base+48..63
        h4v b0 = cvt_relu4(a0);
        h4v b1 = cvt_relu4(a1);
        h4v b2 = cvt_relu4(a2);
        h4v b3 = cvt_relu4(a3);

        // ---- 5 mid layers: 4 independent chains ----
        #define MIDLAYER(W)                                    \
            a0 = mfma16(W, b0, z4);  a1 = mfma16(W, b1, z4);   \
            a2 = mfma16(W, b2, z4);  a3 = mfma16(W, b3, z4);   \
            b0 = cvt_relu4(a0);  b1 = cvt_relu4(a1);           \
            b2 = cvt_relu4(a2);  b3 = cvt_relu4(a3);
        MIDLAYER(wm0)
        MIDLAYER(wm1)
        MIDLAYER(wm2)
        MIDLAYER(wm3)
        MIDLAYER(wm4)
        #undef MIDLAYER

        // ---- output layer: wo_t routes tile t's rows to lane-group t ----
        a0 = mfma16(wo0, b0, z4);
        a1 = mfma16(wo1, b1, z4);
        a2 = mfma16(wo2, b2, z4);
        a3 = mfma16(wo3, b3, z4);

        f2 o = selstore(a0, a1, a2, a3);   // point base + lane

        if (base + 64 <= n) {
            out[base + lane] = o;          // one contiguous 512B line/wave
        } else if (base + lane < n) {
            out[base + lane] = o;
        }

        xy = xyn;
    }
}

extern "C" void kernel_launch(void* const* d_in, const int* in_sizes, int n_in,
                              void* d_out, int out_size, void* d_ws, size_t ws_size,
                              hipStream_t stream) {
    const float* x     = (const float*)d_in[0];
    const float* w_in  = (const float*)d_in[1];
    const float* w_mid = (const float*)d_in[2];
    const float* w_out = (const float*)d_in[3];

    int n = in_sizes[0] / 2;          // number of points
    int nchunks = (n + 255) / 256;
    int blocks = nchunks < 2048 ? nchunks : 2048;  // persistent

    denoiser_mfma16<<<blocks, 256, 0, stream>>>(
        (const f2*)x, w_in, w_mid, w_out, (f2*)d_out, n);
}

// Round 22
// 27.967 us; speedup vs baseline: 1.2889x; 1.0098x over previous
//
#include <hip/hip_runtime.h>

// Denoiser MLP (2->16, 5x 16->16, 16->2), fp32 in/out, via v_mfma_f32_16x16x16_f16.
// R22 = exact restore of R17, the session optimum (27.66us).
// Final model (fits R3-R21): dur ~= matrix(~10us: 28 MFMA/body x 13.45
// cyc/SIMD) + VALU(~7us: ~130 instr/body x 2cyc) + mem(~10us: 67MB @ 6.7TB/s),
// additive. Ten overlap/residency/shape mechanisms tested R5-R21; only the
// 16-reg->4-reg accumulator shrink (R17) moved the needle (-16%). Legacy
// 16x16x16 is the best shape per useful FLOP for a 16x16 weight matrix
// (13.45 cyc vs K32-padded 19.4 [R19: +30% dur], 32x32-dup 32.3 [R6/R14]).
//
// Mapping (verified R3/R17, absmax 7.8e-3):
//   per layer D = A*B, A = weights (16x16), B = activations^T
//   A frag: lane l holds A[i=l&15][k=4*(l>>4)+j], j=0..3
//   B frag: lane l holds B[k=4*(l>>4)+j][n=l&15]
//   D frag: lane l holds D[i=4*(l>>4)+r][n=l&15], r=0..3
//   D layout == B layout -> layers chain in-register, zero cross-lane.
// Input trick: bin = pack2(cvtpk(x,y),0) puts lane l's point at k=4g+{0,1},
// col l&15; wi_t (W_in at k-slots {4t,4t+1}, held by g==t lanes) selects
// group-t lanes' points -> tile t = pts base+16t..16t+15; one cvtpk feeds
// all 4 input MFMAs. Output: wo rows 0,1 -> D regs 0,1 @ group 0.

typedef _Float16 h4v __attribute__((ext_vector_type(4)));
typedef float f4 __attribute__((ext_vector_type(4)));
typedef float f2 __attribute__((ext_vector_type(2)));
typedef unsigned int u32;
typedef u32 u2v __attribute__((ext_vector_type(2)));

static __device__ __forceinline__ f4 mfma16(h4v a, h4v b, f4 c) {
    return __builtin_amdgcn_mfma_f32_16x16x16f16(a, b, c, 0, 0, 0);
}

static __device__ __forceinline__ u32 cvtpk(float a, float b) {
    return __builtin_bit_cast(u32, __builtin_amdgcn_cvt_pkrtz(a, b));
}

static __device__ __forceinline__ h4v pack2(u32 lo, u32 hi) {
    u2v p = {lo, hi};
    return __builtin_bit_cast(h4v, p);
}

// weight A-fragment: rows = lane&15, cols 4g..4g+3
static __device__ __forceinline__ h4v wfrag(const float* row, int g) {
    const f4* r4 = (const f4*)row;
    f4 q = r4[g];
    return pack2(cvtpk(q.x, q.y), cvtpk(q.z, q.w));
}

// relu + cvt of D regs 0-3 -> next layer's B fragment (order-preserving)
static __device__ __forceinline__ h4v cvt_relu4(f4 a) {
    h4v hb = pack2(cvtpk(a[0], a[1]), cvtpk(a[2], a[3]));
    const h4v z = {};
    return __builtin_elementwise_max(hb, z);   // 2x v_pk_max_f16
}

__global__ __launch_bounds__(256, 5) void denoiser_mfma16(
    const f2* __restrict__ x,        // [N] points (x0,x1)
    const float* __restrict__ w_in,  // [16][2]
    const float* __restrict__ w_mid, // [5][16][16]
    const float* __restrict__ w_out, // [2][16]
    f2* __restrict__ out,            // [N] (o0,o1)
    int n)
{
    const int lane = threadIdx.x & 63;
    const int nn   = lane & 15;   // A-row / point-in-tile
    const int g    = lane >> 4;   // k-group (4 k per group)
    const int wave = threadIdx.x >> 6;

    const h4v hz = {};

    // ---- one-time weight fragments ----
    // input variants: wi_t nonzero only for g==t lanes, k-slots j0,j1 = W_in row
    u32 wxy = cvtpk(w_in[2 * nn], w_in[2 * nn + 1]);
    h4v wi0 = g == 0 ? pack2(wxy, 0u) : hz;
    h4v wi1 = g == 1 ? pack2(wxy, 0u) : hz;
    h4v wi2 = g == 2 ? pack2(wxy, 0u) : hz;
    h4v wi3 = g == 3 ? pack2(wxy, 0u) : hz;

    h4v wm0 = wfrag(w_mid + 0 * 256 + nn * 16, g);
    h4v wm1 = wfrag(w_mid + 1 * 256 + nn * 16, g);
    h4v wm2 = wfrag(w_mid + 2 * 256 + nn * 16, g);
    h4v wm3 = wfrag(w_mid + 3 * 256 + nn * 16, g);
    h4v wm4 = wfrag(w_mid + 4 * 256 + nn * 16, g);

    h4v wo = nn < 2 ? wfrag(w_out + nn * 16, g) : hz;

    // one-time pin: zero C-operand (4 regs) resident, un-rematerializable
    f4 z4 = {};
    asm("" : "+v"(z4));

    const int nchunks = (n + 255) >> 8;     // 256-pt block chunks
    const int stride  = gridDim.x;
    const int nm1     = n - 1;

    auto loadx = [&](int c) -> f2 {
        int pi = c * 256 + wave * 64 + lane;
        return x[pi < n ? pi : nm1];
    };

    int c = blockIdx.x;
    f2 xy = loadx(c);

    for (; c < nchunks; c += stride) {
        // depth-1 prefetch of next chunk (issued before the compute chain)
        const int cn = c + stride;
        f2 xyn = loadx(cn < nchunks ? cn : c);

        const int base = c * 256 + wave * 64;

        // ---- input layer: ONE packed bin, 4 group-selecting A variants ----
        h4v bin = pack2(cvtpk(xy.x, xy.y), 0u);
        f4 a0 = mfma16(wi0, bin, z4);   // pts base+ 0..15
        f4 a1 = mfma16(wi1, bin, z4);   // pts base+16..31
        f4 a2 = mfma16(wi2, bin, z4);   // pts base+32..47
        f4 a3 = mfma16(wi3, bin, z4);   // pts base+48..63
        h4v b0 = cvt_relu4(a0);
        h4v b1 = cvt_relu4(a1);
        h4v b2 = cvt_relu4(a2);
        h4v b3 = cvt_relu4(a3);

        // ---- 5 mid layers: 4 independent tiles (ILP) ----
        a0 = mfma16(wm0, b0, z4);  a1 = mfma16(wm0, b1, z4);
        a2 = mfma16(wm0, b2, z4);  a3 = mfma16(wm0, b3, z4);
        b0 = cvt_relu4(a0);  b1 = cvt_relu4(a1);
        b2 = cvt_relu4(a2);  b3 = cvt_relu4(a3);

        a0 = mfma16(wm1, b0, z4);  a1 = mfma16(wm1, b1, z4);
        a2 = mfma16(wm1, b2, z4);  a3 = mfma16(wm1, b3, z4);
        b0 = cvt_relu4(a0);  b1 = cvt_relu4(a1);
        b2 = cvt_relu4(a2);  b3 = cvt_relu4(a3);

        a0 = mfma16(wm2, b0, z4);  a1 = mfma16(wm2, b1, z4);
        a2 = mfma16(wm2, b2, z4);  a3 = mfma16(wm2, b3, z4);
        b0 = cvt_relu4(a0);  b1 = cvt_relu4(a1);
        b2 = cvt_relu4(a2);  b3 = cvt_relu4(a3);

        a0 = mfma16(wm3, b0, z4);  a1 = mfma16(wm3, b1, z4);
        a2 = mfma16(wm3, b2, z4);  a3 = mfma16(wm3, b3, z4);
        b0 = cvt_relu4(a0);  b1 = cvt_relu4(a1);
        b2 = cvt_relu4(a2);  b3 = cvt_relu4(a3);

        a0 = mfma16(wm4, b0, z4);  a1 = mfma16(wm4, b1, z4);
        a2 = mfma16(wm4, b2, z4);  a3 = mfma16(wm4, b3, z4);
        b0 = cvt_relu4(a0);  b1 = cvt_relu4(a1);
        b2 = cvt_relu4(a2);  b3 = cvt_relu4(a3);

        // ---- output layer: rows 0,1 -> regs 0,1 @ group 0 ----
        a0 = mfma16(wo, b0, z4);
        a1 = mfma16(wo, b1, z4);
        a2 = mfma16(wo, b2, z4);
        a3 = mfma16(wo, b3, z4);

        if (lane < 16) {
            int p0 = base + nn;
            if (base + 64 <= n) {
                out[p0]      = (f2){a0[0], a0[1]};
                out[p0 + 16] = (f2){a1[0], a1[1]};
                out[p0 + 32] = (f2){a2[0], a2[1]};
                out[p0 + 48] = (f2){a3[0], a3[1]};
            } else {
                if (p0 < n)      out[p0]      = (f2){a0[0], a0[1]};
                if (p0 + 16 < n) out[p0 + 16] = (f2){a1[0], a1[1]};
                if (p0 + 32 < n) out[p0 + 32] = (f2){a2[0], a2[1]};
                if (p0 + 48 < n) out[p0 + 48] = (f2){a3[0], a3[1]};
            }
        }

        xy = xyn;
    }
}

extern "C" void kernel_launch(void* const* d_in, const int* in_sizes, int n_in,
                              void* d_out, int out_size, void* d_ws, size_t ws_size,
                              hipStream_t stream) {
    const float* x     = (const float*)d_in[0];
    const float* w_in  = (const float*)d_in[1];
    const float* w_mid = (const float*)d_in[2];
    const float* w_out = (const float*)d_in[3];

    int n = in_sizes[0] / 2;          // number of points
    int nchunks = (n + 255) / 256;
    int blocks = nchunks < 2048 ? nchunks : 2048;  // persistent

    denoiser_mfma16<<<blocks, 256, 0, stream>>>(
        (const f2*)x, w_in, w_mid, w_out, (f2*)d_out, n);
}